// Round 12
// baseline (1025.158 us; speedup 1.0000x reference)
//
#include <hip/hip_runtime.h>
#include <hip/hip_bf16.h>

// SAGAN attention block: B=4, C=256, H=W=64 (N=4096).
// Round 12 (= r11 + intrinsic-name fix): KVBLK 16 => LDS/block 32KB => 4
// blocks/CU (4 waves/SIMD at VGPR<=128) -- attacks the measured 39% LDS-pipe
// utilization (latency-bound at 2 waves/SIMD). PV uses the legacy
// mfma_f32_16x16x16f16 whose B-slot layout (k=4g+q) equals swapped-QK output
// directly: P lane-local, no key permutation. Key-split x4 + merge.

typedef short short8 __attribute__((ext_vector_type(8)));
typedef short short4v __attribute__((ext_vector_type(4)));
typedef float f32x4 __attribute__((ext_vector_type(4)));
typedef _Float16 f16x8 __attribute__((ext_vector_type(8)));
typedef _Float16 f16x4 __attribute__((ext_vector_type(4)));
typedef unsigned short u16;
typedef unsigned int u32;

#define DEV static __device__ __forceinline__
#define MFMA(a, b, c)    __builtin_amdgcn_mfma_f32_16x16x32_bf16(a, b, c, 0, 0, 0)
#define MFMA16(a, b, c)  __builtin_amdgcn_mfma_f32_16x16x32_f16(a, b, c, 0, 0, 0)
#define MFMA16S(a, b, c) __builtin_amdgcn_mfma_f32_16x16x16f16(a, b, c, 0, 0, 0)

DEV u16 b16(float x) {
    __hip_bfloat16 h = __float2bfloat16(x);
    return *reinterpret_cast<u16*>(&h);
}
DEV float f16f(u16 u) {
    union { unsigned int ui; float f; } c;
    c.ui = ((unsigned int)u) << 16;
    return c.f;
}
DEV u16 h16(float x) {
    union { _Float16 h; u16 u; } c;
    c.h = (_Float16)x;
    return c.u;
}
DEV short8 ld8(const u16* p) { return *reinterpret_cast<const short8*>(p); }
DEV f16x8 ldh8(const u16* p) { return *reinterpret_cast<const f16x8*>(p); }

DEV u32 cvtpk(float a, float b) {  // packed f16 (rtz): lo=a, hi=b
    u32 r;
    asm("v_cvt_pkrtz_f16_f32 %0, %1, %2" : "=v"(r) : "v"(a), "v"(b));
    return r;
}

// async global->LDS, 16B per lane; dst is wave-uniform base, HW adds lane*16
DEV void gload16(const void* g, void* l) {
    __builtin_amdgcn_global_load_lds(
        (const __attribute__((address_space(1))) unsigned int*)g,
        (__attribute__((address_space(3))) unsigned int*)l, 16, 0, 0);
}

// ---- workspace byte offsets ----
constexpr size_t OFF_WFH = 0;         // 128K bf16 hi
constexpr size_t OFF_WFL = 131072;
constexpr size_t OFF_WGH = 262144;
constexpr size_t OFF_WGL = 393216;
constexpr size_t OFF_WHB = 524288;    // 128K bf16
constexpr size_t OFF_WVB = 655360;    // 128K fp16
constexpr size_t OFF_ML  = 786432;    // 512K f32 pairs (4 splits x 16384 x {m,l})
constexpr size_t OFF_F   = 1310720;   // 8M fp16 [m][c]   (K source)
constexpr size_t OFF_G   = OFF_F + 8388608;    // 8M fp16 [m][c]  (Q source)
constexpr size_t OFF_H   = OFF_G + 8388608;    // 8M fp16 [b][c][n] (V source, natural)
constexpr size_t OFF_XTH = OFF_H + 8388608;    // bf16 [m][c], dead after conv_h
constexpr size_t OFF_XTL = OFF_XTH + 8388608;
constexpr size_t OFF_OP  = OFF_XTH;            // 32M fp16 (4 splits), aliases dead Xt + tail
constexpr size_t OFF_OT  = OFF_F;              // 8M fp16, aliases dead F
// high-water mark = OFF_OP + 33554432 = 60,030,976 bytes (round-2/5-proven)

// ---------------- weight prep ----------------
__global__ __launch_bounds__(256) void k_prep_w(
    const float* __restrict__ Wf, const float* __restrict__ Wg,
    const float* __restrict__ Wh, const float* __restrict__ Wv,
    u16* WFH, u16* WFL, u16* WGH, u16* WGL, u16* WHB, u16* WVB) {
    int i = blockIdx.x * 256 + threadIdx.x;
    float fv = Wf[i];
    u16 fh = b16(fv);
    WFH[i] = fh;
    WFL[i] = b16(fv - f16f(fh));
    float gv = Wg[i];
    u16 gh = b16(gv);
    WGH[i] = gh;
    WGL[i] = b16(gv - f16f(gh));
    WHB[i] = b16(Wh[i]);
    WVB[i] = h16(Wv[i]);
}

// ---------------- x transpose + split ----------------
__global__ __launch_bounds__(256) void k_prep_x(const float* __restrict__ x, u16* XtH, u16* XtL) {
    __shared__ float lds[64][65];
    int bid = blockIdx.x;
    int b = bid >> 8, rem = bid & 255, ct = rem >> 6, nt = rem & 63;
    int tid = threadIdx.x;
    int tx = tid & 63, ty = tid >> 6;
    const float* src = x + ((size_t)(b * 256 + ct * 64)) * 4096 + nt * 64;
#pragma unroll
    for (int k = 0; k < 16; ++k) {
        int cl = ty * 16 + k;
        lds[cl][tx] = src[(size_t)cl * 4096 + tx];
    }
    __syncthreads();
    int nl = tid >> 2, cg = tid & 3;
    short8 h0, h1, l0, l1;
#pragma unroll
    for (int j = 0; j < 8; ++j) {
        float v = lds[cg * 16 + j][nl];
        u16 hb = b16(v);
        h0[j] = (short)hb;
        l0[j] = (short)b16(v - f16f(hb));
    }
#pragma unroll
    for (int j = 8; j < 16; ++j) {
        float v = lds[cg * 16 + j][nl];
        u16 hb = b16(v);
        h1[j - 8] = (short)hb;
        l1[j - 8] = (short)b16(v - f16f(hb));
    }
    size_t dst = ((size_t)(b * 4096 + nt * 64 + nl)) * 256 + ct * 64 + cg * 16;
    *reinterpret_cast<short8*>(XtH + dst) = h0;
    *reinterpret_cast<short8*>(XtH + dst + 8) = h1;
    *reinterpret_cast<short8*>(XtL + dst) = l0;
    *reinterpret_cast<short8*>(XtL + dst + 8) = l1;
}

// ---------------- conv f,g: 3-pass split-bf16 MFMA, fp16 out ----------------
__global__ __launch_bounds__(256) void k_conv_fg(
    const u16* __restrict__ XtH, const u16* __restrict__ XtL,
    const u16* __restrict__ WFH, const u16* __restrict__ WFL,
    const u16* __restrict__ WGH, const u16* __restrict__ WGL,
    const float* __restrict__ bf, const float* __restrict__ bg,
    u16* F, u16* G) {
    int bidm = blockIdx.x & 255, bido = blockIdx.x >> 8;
    int w = threadIdx.x >> 6, lane = threadIdx.x & 63, r = lane & 15, g = lane >> 4;
    int m0 = bidm * 64 + w * 16, o0 = bido * 64;
    f32x4 fa[4], ga[4];
#pragma unroll
    for (int i = 0; i < 4; ++i) { fa[i] = {0.f, 0.f, 0.f, 0.f}; ga[i] = {0.f, 0.f, 0.f, 0.f}; }
    const u16* arh = XtH + (size_t)(m0 + r) * 256;
    const u16* arl = XtL + (size_t)(m0 + r) * 256;
#pragma unroll
    for (int ks = 0; ks < 8; ++ks) {
        int k0 = ks * 32 + 8 * g;
        short8 ah = ld8(arh + k0);
        short8 al = ld8(arl + k0);
#pragma unroll
        for (int ot = 0; ot < 4; ++ot) {
            size_t wrow = (size_t)(o0 + ot * 16 + r) * 256 + k0;
            short8 wfh = ld8(WFH + wrow), wfl = ld8(WFL + wrow);
            short8 wgh = ld8(WGH + wrow), wgl = ld8(WGL + wrow);
            fa[ot] = MFMA(ah, wfh, fa[ot]);
            fa[ot] = MFMA(ah, wfl, fa[ot]);
            fa[ot] = MFMA(al, wfh, fa[ot]);
            ga[ot] = MFMA(ah, wgh, ga[ot]);
            ga[ot] = MFMA(ah, wgl, ga[ot]);
            ga[ot] = MFMA(al, wgh, ga[ot]);
        }
    }
#pragma unroll
    for (int ot = 0; ot < 4; ++ot) {
#pragma unroll
        for (int q = 0; q < 4; ++q) {
            int row = m0 + 4 * g + q;
            int col = o0 + ot * 16 + r;
            size_t idx = (size_t)row * 256 + col;
            F[idx] = h16(fa[ot][q] + bf[col]);
            G[idx] = h16(ga[ot][q] + bg[col]);
        }
    }
}

// ---------------- conv h: bf16 MFMA, fp16 out, layout [b][c][n] (natural) ----------------
__global__ __launch_bounds__(256) void k_conv_h(
    const u16* __restrict__ WHB, const u16* __restrict__ XtH,
    const float* __restrict__ bh, u16* Hb) {
    int bidn = blockIdx.x & 255, bido = blockIdx.x >> 8;
    int w = threadIdx.x >> 6, lane = threadIdx.x & 63, r = lane & 15, g = lane >> 4;
    int o0 = bido * 64 + w * 16, n0 = bidn * 64;
    f32x4 acc[4];
#pragma unroll
    for (int i = 0; i < 4; ++i) acc[i] = {0.f, 0.f, 0.f, 0.f};
    const u16* arow = WHB + (size_t)(o0 + r) * 256;
#pragma unroll
    for (int ks = 0; ks < 8; ++ks) {
        int k0 = ks * 32 + 8 * g;
        short8 a = ld8(arow + k0);
#pragma unroll
        for (int ntl = 0; ntl < 4; ++ntl) {
            short8 bb = ld8(XtH + (size_t)(n0 + ntl * 16 + r) * 256 + k0);
            acc[ntl] = MFMA(a, bb, acc[ntl]);
        }
    }
#pragma unroll
    for (int ntl = 0; ntl < 4; ++ntl) {
#pragma unroll
        for (int q = 0; q < 4; ++q) {
            int o = o0 + 4 * g + q;
            int nf = n0 + ntl * 16 + r;
            int bb = nf >> 12, n = nf & 4095;
            Hb[((size_t)(bb * 256 + o)) * 4096 + n] = h16(acc[ntl][q] + bh[o]);
        }
    }
}

// ---------------- flash attention: KVBLK=16, 4 blocks/CU, lane-local P ----------------
__global__ __launch_bounds__(256, 4) void k_attn(
    const u16* __restrict__ F, const u16* __restrict__ G,
    const u16* __restrict__ Hb, u16* __restrict__ OP, float* __restrict__ ML) {
    // K tile [16 keys][256 c] fp16, 8KB each, swizzle byte ^= (row&7)<<4.
    // V tile [256 c][16 keys] fp16, 8KB each, natural (b64 reads are uniform).
    __shared__ u16 Kd[2][4096];
    __shared__ u16 Vd[2][4096];

    int bid = blockIdx.x;            // 1024 = 8 xcd * 128; 4 blocks/CU
    int xcd = bid & 7, idx = bid >> 3;
    int b = xcd >> 1;                // batch
    int ks = ((idx & 1) << 1) | (xcd & 1);  // key-quarter 0..3
    int qb = idx >> 1;               // 0..63
    int tid = threadIdx.x;
    int w = tid >> 6, lane = tid & 63, r = lane & 15, g = lane >> 4;
    int j0 = qb * 64 + w * 16;       // wave's 16 queries
    const float L2E = 1.4426950408889634f;

    // Q as QK B-operand (col = query r): Qf[k] = Q[j0+r][k*32 + 8g .. +7]
    f16x8 Qf[8];
    {
        const u16* q = G + (size_t)(b * 4096 + j0 + r) * 256;
#pragma unroll
        for (int k = 0; k < 8; ++k) Qf[k] = ldh8(q + k * 32 + 8 * g);
    }
    // O[ct][q] = O[channel ct*16 + 4g + q][query j0 + r]
    f32x4 O[16];
#pragma unroll
    for (int i = 0; i < 16; ++i) O[i] = {0.f, 0.f, 0.f, 0.f};
    float m = -1e30f, l = 0.f;       // per-query (lane-scalar)

    const char* Fb  = (const char*)(F + (size_t)b * 4096 * 256);
    const char* Hbb = (const char*)(Hb + (size_t)b * 256 * 4096);

    // per-lane pre-swizzled stage source offsets (dest is linear)
    int ksrc[2], vsrc[2];
#pragma unroll
    for (int t = 0; t < 2; ++t) {
        int d = (w * 2 + t) * 1024 + lane * 16;
        int row = d >> 9, col = d & 511;
        ksrc[t] = row * 512 + (col ^ ((row & 7) << 4));
        int c = d >> 5, kb2 = d & 31;
        vsrc[t] = c * 8192 + kb2;
    }

#define STAGE(bufn, I0)                                                         \
    do {                                                                        \
        const char* kb_ = Fb + (size_t)(I0) * 512;                              \
        const char* vb_ = Hbb + (size_t)(I0) * 2;                               \
        char* kl = (char*)Kd[bufn];                                             \
        char* vl = (char*)Vd[bufn];                                             \
        _Pragma("unroll") for (int t = 0; t < 2; ++t)                           \
            gload16(kb_ + ksrc[t], kl + (w * 2 + t) * 1024);                    \
        _Pragma("unroll") for (int t = 0; t < 2; ++t)                           \
            gload16(vb_ + vsrc[t], vl + (w * 2 + t) * 1024);                    \
    } while (0)

    int i0beg = ks * 1024;
    STAGE(0, i0beg);   // prologue
    __syncthreads();   // drains vmcnt(0): tile 0 ready

    for (int it = 0; it < 64; ++it) {
        int cur = it & 1;
        if (it + 1 < 64) STAGE(cur ^ 1, i0beg + (it + 1) * 16);  // fly under compute

        const char* Kl = (const char*)Kd[cur];
        const u16* Vl = Vd[cur];

        // ---- QK^T swapped: A = K (rows = keys), B = Q (regs).
        // s0[q] = S[key 4g+q][query r]
        f32x4 s0 = {0.f, 0.f, 0.f, 0.f};
        __builtin_amdgcn_s_setprio(1);
        {
            const char* kr = Kl + r * 512;
            int sw = (r & 7) << 4;
#pragma unroll
            for (int k = 0; k < 8; ++k) {
                f16x8 ka = *reinterpret_cast<const f16x8*>(kr + ((k * 64 + 16 * g) ^ sw));
                s0 = MFMA16(ka, Qf[k], s0);
            }
        }
        __builtin_amdgcn_s_setprio(0);

        // ---- softmax: lane holds 4 scores of query r; reduce over g-lanes via shfl ----
        float v = fmaxf(fmaxf(s0[0], s0[1]), fmaxf(s0[2], s0[3]));
        v = fmaxf(v, __shfl_xor(v, 16));
        v = fmaxf(v, __shfl_xor(v, 32));
        float grow = v - m;
        if (__all(grow <= 8.0f)) {  // T13 defer-max: skip rescale
#pragma unroll
            for (int q = 0; q < 4; ++q) s0[q] = exp2f((s0[q] - m) * L2E);
            float rs = (s0[0] + s0[1]) + (s0[2] + s0[3]);
            rs += __shfl_xor(rs, 16);
            rs += __shfl_xor(rs, 32);
            l += rs;
        } else {
            float mn = fmaxf(m, v);
            float corr = exp2f((m - mn) * L2E);
            m = mn;
#pragma unroll
            for (int q = 0; q < 4; ++q) s0[q] = exp2f((s0[q] - m) * L2E);
            float rs = (s0[0] + s0[1]) + (s0[2] + s0[3]);
            rs += __shfl_xor(rs, 16);
            rs += __shfl_xor(rs, 32);
            l = l * corr + rs;
#pragma unroll
            for (int ct = 0; ct < 16; ++ct) O[ct] *= corr;  // whole lane = one query
        }

        // ---- P -> PV B-frag: LANE-LOCAL by construction of 16x16x16 layout ----
        union { u32 wd[2]; f16x4 fr; } pb;
        pb.wd[0] = cvtpk(s0[0], s0[1]);
        pb.wd[1] = cvtpk(s0[2], s0[3]);

        // ---- PV (16x16x16): O[c][j] += V[c][k] * P[k][j]; A = V b64 reads ----
        __builtin_amdgcn_s_setprio(1);
#pragma unroll
        for (int ct = 0; ct < 16; ++ct) {
            f16x4 va = *reinterpret_cast<const f16x4*>(Vl + (ct * 16 + r) * 16 + 4 * g);
            O[ct] = MFMA16S(va, pb.fr, O[ct]);
        }
        __builtin_amdgcn_s_setprio(0);

        __syncthreads();  // drains vmcnt (next tile landed during compute); buffer reuse safe
    }
#undef STAGE

    // ---- normalize (lane-scalar) + packed store: O[ct][q] -> channel ct*16+4g+q ----
    float inv = 1.f / l;
    size_t mrow = (size_t)ks * 16384 + b * 4096 + j0 + r;
#pragma unroll
    for (int ct = 0; ct < 16; ++ct) {
        short4v pk;
#pragma unroll
        for (int q = 0; q < 4; ++q) pk[q] = (short)h16(O[ct][q] * inv);
        *reinterpret_cast<short4v*>(OP + mrow * 256 + ct * 16 + 4 * g) = pk;
    }
    if (g == 0) {
        size_t mi = mrow * 2;
        ML[mi] = m;
        ML[mi + 1] = l;
    }
}

// ---------------- merge key-splits (x4, normalized partials) -> OT fp16 [m][c] ----------------
__global__ __launch_bounds__(256) void k_merge(
    const u16* __restrict__ OP, const float* __restrict__ ML, u16* __restrict__ OT) {
    int t = blockIdx.x * 256 + threadIdx.x;  // 524288 threads
    int m = t >> 5;
    int c0 = (t & 31) * 8;
    const float L2E = 1.4426950408889634f;
    float mm[4], ll[4];
    float M = -1e30f;
#pragma unroll
    for (int ks = 0; ks < 4; ++ks) {
        size_t mi = ((size_t)ks * 16384 + m) * 2;
        mm[ks] = ML[mi];
        ll[ks] = ML[mi + 1];
        M = fmaxf(M, mm[ks]);
    }
    float wl[4], L = 0.f;
#pragma unroll
    for (int ks = 0; ks < 4; ++ks) {
        wl[ks] = exp2f((mm[ks] - M) * L2E) * ll[ks];
        L += wl[ks];
    }
    float inv = 1.f / L;
    float acc[8];
#pragma unroll
    for (int j = 0; j < 8; ++j) acc[j] = 0.f;
#pragma unroll
    for (int ks = 0; ks < 4; ++ks) {
        f16x8 v = ldh8(OP + ((size_t)ks * 16384 + m) * 256 + c0);
#pragma unroll
        for (int j = 0; j < 8; ++j) acc[j] += wl[ks] * (float)v[j];
    }
    short8 outp;
#pragma unroll
    for (int j = 0; j < 8; ++j) outp[j] = (short)h16(acc[j] * inv);
    *reinterpret_cast<short8*>(OT + (size_t)m * 256 + c0) = outp;
}

// ---------------- final conv: fp16 MFMA, f32 out ----------------
__global__ __launch_bounds__(256) void k_conv_out(
    const u16* __restrict__ WVB, const u16* __restrict__ OT,
    const float* __restrict__ bv, float* __restrict__ out) {
    int bidn = blockIdx.x & 255, bido = blockIdx.x >> 8;
    int w = threadIdx.x >> 6, lane = threadIdx.x & 63, r = lane & 15, g = lane >> 4;
    int o0 = bido * 64 + w * 16, n0 = bidn * 64;
    f32x4 acc[4];
#pragma unroll
    for (int i = 0; i < 4; ++i) acc[i] = {0.f, 0.f, 0.f, 0.f};
    const u16* arow = WVB + (size_t)(o0 + r) * 256;
#pragma unroll
    for (int ks = 0; ks < 8; ++ks) {
        int k0 = ks * 32 + 8 * g;
        f16x8 a = ldh8(arow + k0);
#pragma unroll
        for (int ntl = 0; ntl < 4; ++ntl) {
            f16x8 bb = ldh8(OT + (size_t)(n0 + ntl * 16 + r) * 256 + k0);
            acc[ntl] = MFMA16(a, bb, acc[ntl]);
        }
    }
#pragma unroll
    for (int ntl = 0; ntl < 4; ++ntl) {
#pragma unroll
        for (int q = 0; q < 4; ++q) {
            int o = o0 + 4 * g + q;
            int nf = n0 + ntl * 16 + r;
            int bb = nf >> 12, n = nf & 4095;
            out[((size_t)(bb * 256 + o)) * 4096 + n] = acc[ntl][q] + bv[o];
        }
    }
}

extern "C" void kernel_launch(void* const* d_in, const int* in_sizes, int n_in,
                              void* d_out, int out_size, void* d_ws, size_t ws_size,
                              hipStream_t stream) {
    const float* x  = (const float*)d_in[0];
    const float* Wf = (const float*)d_in[1];
    const float* bf = (const float*)d_in[2];
    const float* Wg = (const float*)d_in[3];
    const float* bg = (const float*)d_in[4];
    const float* Wh = (const float*)d_in[5];
    const float* bh = (const float*)d_in[6];
    const float* Wv = (const float*)d_in[7];
    const float* bv = (const float*)d_in[8];
    float* out = (float*)d_out;
    char* ws = (char*)d_ws;

    u16* WFH = (u16*)(ws + OFF_WFH);
    u16* WFL = (u16*)(ws + OFF_WFL);
    u16* WGH = (u16*)(ws + OFF_WGH);
    u16* WGL = (u16*)(ws + OFF_WGL);
    u16* WHB = (u16*)(ws + OFF_WHB);
    u16* WVB = (u16*)(ws + OFF_WVB);
    float* ML = (float*)(ws + OFF_ML);
    u16* F   = (u16*)(ws + OFF_F);
    u16* G   = (u16*)(ws + OFF_G);
    u16* H   = (u16*)(ws + OFF_H);
    u16* XTH = (u16*)(ws + OFF_XTH);
    u16* XTL = (u16*)(ws + OFF_XTL);
    u16* OP  = (u16*)(ws + OFF_OP);   // aliases Xt (dead after convs)
    u16* OT  = (u16*)(ws + OFF_OT);   // aliases F (dead after attn)

    k_prep_w<<<256, 256, 0, stream>>>(Wf, Wg, Wh, Wv, WFH, WFL, WGH, WGL, WHB, WVB);
    k_prep_x<<<1024, 256, 0, stream>>>(x, XTH, XTL);
    k_conv_fg<<<1024, 256, 0, stream>>>(XTH, XTL, WFH, WFL, WGH, WGL, bf, bg, F, G);
    k_conv_h<<<1024, 256, 0, stream>>>(WHB, XTH, bh, H);
    k_attn<<<1024, 256, 0, stream>>>(F, G, H, OP, ML);
    k_merge<<<2048, 256, 0, stream>>>(OP, ML, OT);
    k_conv_out<<<1024, 256, 0, stream>>>(WVB, OT, bv, out);
}

// Round 13
// 481.027 us; speedup vs baseline: 2.1312x; 2.1312x over previous
//
#include <hip/hip_runtime.h>
#include <hip/hip_bf16.h>

// SAGAN attention block: B=4, C=256, H=W=64 (N=4096).
// Round 13 (= r12 with the launch-bounds cap removed): KVBLK=16 => 32KB LDS
// => LDS permits 4 blocks/CU; natural register allocation (~112, per r10's
// identical-shape kernel) => VGPR permits 4 waves/SIMD. r12's (256,4) capped
// unified regs at 128 => O-accumulator spilled => 4.2GB HBM traffic (900us).
// NEVER set min-waves on this kernel family; the allocator fits naturally.

typedef short short8 __attribute__((ext_vector_type(8)));
typedef short short4v __attribute__((ext_vector_type(4)));
typedef float f32x4 __attribute__((ext_vector_type(4)));
typedef _Float16 f16x8 __attribute__((ext_vector_type(8)));
typedef _Float16 f16x4 __attribute__((ext_vector_type(4)));
typedef unsigned short u16;
typedef unsigned int u32;

#define DEV static __device__ __forceinline__
#define MFMA(a, b, c)    __builtin_amdgcn_mfma_f32_16x16x32_bf16(a, b, c, 0, 0, 0)
#define MFMA16(a, b, c)  __builtin_amdgcn_mfma_f32_16x16x32_f16(a, b, c, 0, 0, 0)
#define MFMA16S(a, b, c) __builtin_amdgcn_mfma_f32_16x16x16f16(a, b, c, 0, 0, 0)

DEV u16 b16(float x) {
    __hip_bfloat16 h = __float2bfloat16(x);
    return *reinterpret_cast<u16*>(&h);
}
DEV float f16f(u16 u) {
    union { unsigned int ui; float f; } c;
    c.ui = ((unsigned int)u) << 16;
    return c.f;
}
DEV u16 h16(float x) {
    union { _Float16 h; u16 u; } c;
    c.h = (_Float16)x;
    return c.u;
}
DEV short8 ld8(const u16* p) { return *reinterpret_cast<const short8*>(p); }
DEV f16x8 ldh8(const u16* p) { return *reinterpret_cast<const f16x8*>(p); }

DEV u32 cvtpk(float a, float b) {  // packed f16 (rtz): lo=a, hi=b
    u32 r;
    asm("v_cvt_pkrtz_f16_f32 %0, %1, %2" : "=v"(r) : "v"(a), "v"(b));
    return r;
}

// async global->LDS, 16B per lane; dst is wave-uniform base, HW adds lane*16
DEV void gload16(const void* g, void* l) {
    __builtin_amdgcn_global_load_lds(
        (const __attribute__((address_space(1))) unsigned int*)g,
        (__attribute__((address_space(3))) unsigned int*)l, 16, 0, 0);
}

// ---- workspace byte offsets ----
constexpr size_t OFF_WFH = 0;         // 128K bf16 hi
constexpr size_t OFF_WFL = 131072;
constexpr size_t OFF_WGH = 262144;
constexpr size_t OFF_WGL = 393216;
constexpr size_t OFF_WHB = 524288;    // 128K bf16
constexpr size_t OFF_WVB = 655360;    // 128K fp16
constexpr size_t OFF_ML  = 786432;    // 512K f32 pairs (4 splits x 16384 x {m,l})
constexpr size_t OFF_F   = 1310720;   // 8M fp16 [m][c]   (K source)
constexpr size_t OFF_G   = OFF_F + 8388608;    // 8M fp16 [m][c]  (Q source)
constexpr size_t OFF_H   = OFF_G + 8388608;    // 8M fp16 [b][c][n] (V source, natural)
constexpr size_t OFF_XTH = OFF_H + 8388608;    // bf16 [m][c], dead after conv_h
constexpr size_t OFF_XTL = OFF_XTH + 8388608;
constexpr size_t OFF_OP  = OFF_XTH;            // 32M fp16 (4 splits), aliases dead Xt + tail
constexpr size_t OFF_OT  = OFF_F;              // 8M fp16, aliases dead F
// high-water mark = OFF_OP + 33554432 = 60,030,976 bytes (round-2/5-proven)

// ---------------- weight prep ----------------
__global__ __launch_bounds__(256) void k_prep_w(
    const float* __restrict__ Wf, const float* __restrict__ Wg,
    const float* __restrict__ Wh, const float* __restrict__ Wv,
    u16* WFH, u16* WFL, u16* WGH, u16* WGL, u16* WHB, u16* WVB) {
    int i = blockIdx.x * 256 + threadIdx.x;
    float fv = Wf[i];
    u16 fh = b16(fv);
    WFH[i] = fh;
    WFL[i] = b16(fv - f16f(fh));
    float gv = Wg[i];
    u16 gh = b16(gv);
    WGH[i] = gh;
    WGL[i] = b16(gv - f16f(gh));
    WHB[i] = b16(Wh[i]);
    WVB[i] = h16(Wv[i]);
}

// ---------------- x transpose + split ----------------
__global__ __launch_bounds__(256) void k_prep_x(const float* __restrict__ x, u16* XtH, u16* XtL) {
    __shared__ float lds[64][65];
    int bid = blockIdx.x;
    int b = bid >> 8, rem = bid & 255, ct = rem >> 6, nt = rem & 63;
    int tid = threadIdx.x;
    int tx = tid & 63, ty = tid >> 6;
    const float* src = x + ((size_t)(b * 256 + ct * 64)) * 4096 + nt * 64;
#pragma unroll
    for (int k = 0; k < 16; ++k) {
        int cl = ty * 16 + k;
        lds[cl][tx] = src[(size_t)cl * 4096 + tx];
    }
    __syncthreads();
    int nl = tid >> 2, cg = tid & 3;
    short8 h0, h1, l0, l1;
#pragma unroll
    for (int j = 0; j < 8; ++j) {
        float v = lds[cg * 16 + j][nl];
        u16 hb = b16(v);
        h0[j] = (short)hb;
        l0[j] = (short)b16(v - f16f(hb));
    }
#pragma unroll
    for (int j = 8; j < 16; ++j) {
        float v = lds[cg * 16 + j][nl];
        u16 hb = b16(v);
        h1[j - 8] = (short)hb;
        l1[j - 8] = (short)b16(v - f16f(hb));
    }
    size_t dst = ((size_t)(b * 4096 + nt * 64 + nl)) * 256 + ct * 64 + cg * 16;
    *reinterpret_cast<short8*>(XtH + dst) = h0;
    *reinterpret_cast<short8*>(XtH + dst + 8) = h1;
    *reinterpret_cast<short8*>(XtL + dst) = l0;
    *reinterpret_cast<short8*>(XtL + dst + 8) = l1;
}

// ---------------- conv f,g: 3-pass split-bf16 MFMA, fp16 out ----------------
__global__ __launch_bounds__(256) void k_conv_fg(
    const u16* __restrict__ XtH, const u16* __restrict__ XtL,
    const u16* __restrict__ WFH, const u16* __restrict__ WFL,
    const u16* __restrict__ WGH, const u16* __restrict__ WGL,
    const float* __restrict__ bf, const float* __restrict__ bg,
    u16* F, u16* G) {
    int bidm = blockIdx.x & 255, bido = blockIdx.x >> 8;
    int w = threadIdx.x >> 6, lane = threadIdx.x & 63, r = lane & 15, g = lane >> 4;
    int m0 = bidm * 64 + w * 16, o0 = bido * 64;
    f32x4 fa[4], ga[4];
#pragma unroll
    for (int i = 0; i < 4; ++i) { fa[i] = {0.f, 0.f, 0.f, 0.f}; ga[i] = {0.f, 0.f, 0.f, 0.f}; }
    const u16* arh = XtH + (size_t)(m0 + r) * 256;
    const u16* arl = XtL + (size_t)(m0 + r) * 256;
#pragma unroll
    for (int ks = 0; ks < 8; ++ks) {
        int k0 = ks * 32 + 8 * g;
        short8 ah = ld8(arh + k0);
        short8 al = ld8(arl + k0);
#pragma unroll
        for (int ot = 0; ot < 4; ++ot) {
            size_t wrow = (size_t)(o0 + ot * 16 + r) * 256 + k0;
            short8 wfh = ld8(WFH + wrow), wfl = ld8(WFL + wrow);
            short8 wgh = ld8(WGH + wrow), wgl = ld8(WGL + wrow);
            fa[ot] = MFMA(ah, wfh, fa[ot]);
            fa[ot] = MFMA(ah, wfl, fa[ot]);
            fa[ot] = MFMA(al, wfh, fa[ot]);
            ga[ot] = MFMA(ah, wgh, ga[ot]);
            ga[ot] = MFMA(ah, wgl, ga[ot]);
            ga[ot] = MFMA(al, wgh, ga[ot]);
        }
    }
#pragma unroll
    for (int ot = 0; ot < 4; ++ot) {
#pragma unroll
        for (int q = 0; q < 4; ++q) {
            int row = m0 + 4 * g + q;
            int col = o0 + ot * 16 + r;
            size_t idx = (size_t)row * 256 + col;
            F[idx] = h16(fa[ot][q] + bf[col]);
            G[idx] = h16(ga[ot][q] + bg[col]);
        }
    }
}

// ---------------- conv h: bf16 MFMA, fp16 out, layout [b][c][n] (natural) ----------------
__global__ __launch_bounds__(256) void k_conv_h(
    const u16* __restrict__ WHB, const u16* __restrict__ XtH,
    const float* __restrict__ bh, u16* Hb) {
    int bidn = blockIdx.x & 255, bido = blockIdx.x >> 8;
    int w = threadIdx.x >> 6, lane = threadIdx.x & 63, r = lane & 15, g = lane >> 4;
    int o0 = bido * 64 + w * 16, n0 = bidn * 64;
    f32x4 acc[4];
#pragma unroll
    for (int i = 0; i < 4; ++i) acc[i] = {0.f, 0.f, 0.f, 0.f};
    const u16* arow = WHB + (size_t)(o0 + r) * 256;
#pragma unroll
    for (int ks = 0; ks < 8; ++ks) {
        int k0 = ks * 32 + 8 * g;
        short8 a = ld8(arow + k0);
#pragma unroll
        for (int ntl = 0; ntl < 4; ++ntl) {
            short8 bb = ld8(XtH + (size_t)(n0 + ntl * 16 + r) * 256 + k0);
            acc[ntl] = MFMA(a, bb, acc[ntl]);
        }
    }
#pragma unroll
    for (int ntl = 0; ntl < 4; ++ntl) {
#pragma unroll
        for (int q = 0; q < 4; ++q) {
            int o = o0 + 4 * g + q;
            int nf = n0 + ntl * 16 + r;
            int bb = nf >> 12, n = nf & 4095;
            Hb[((size_t)(bb * 256 + o)) * 4096 + n] = h16(acc[ntl][q] + bh[o]);
        }
    }
}

// ---------------- flash attention: KVBLK=16, natural regalloc, lane-local P ----------------
__global__ __launch_bounds__(256) void k_attn(
    const u16* __restrict__ F, const u16* __restrict__ G,
    const u16* __restrict__ Hb, u16* __restrict__ OP, float* __restrict__ ML) {
    // K tile [16 keys][256 c] fp16, 8KB each, swizzle byte ^= (row&7)<<4.
    // V tile [256 c][16 keys] fp16, 8KB each, natural (b64 reads are uniform).
    __shared__ u16 Kd[2][4096];
    __shared__ u16 Vd[2][4096];

    int bid = blockIdx.x;            // 1024 = 8 xcd * 128; up to 4 blocks/CU
    int xcd = bid & 7, idx = bid >> 3;
    int b = xcd >> 1;                // batch
    int ks = ((idx & 1) << 1) | (xcd & 1);  // key-quarter 0..3
    int qb = idx >> 1;               // 0..63
    int tid = threadIdx.x;
    int w = tid >> 6, lane = tid & 63, r = lane & 15, g = lane >> 4;
    int j0 = qb * 64 + w * 16;       // wave's 16 queries
    const float L2E = 1.4426950408889634f;

    // Q as QK B-operand (col = query r): Qf[k] = Q[j0+r][k*32 + 8g .. +7]
    f16x8 Qf[8];
    {
        const u16* q = G + (size_t)(b * 4096 + j0 + r) * 256;
#pragma unroll
        for (int k = 0; k < 8; ++k) Qf[k] = ldh8(q + k * 32 + 8 * g);
    }
    // O[ct][q] = O[channel ct*16 + 4g + q][query j0 + r]
    f32x4 O[16];
#pragma unroll
    for (int i = 0; i < 16; ++i) O[i] = {0.f, 0.f, 0.f, 0.f};
    float m = -1e30f, l = 0.f;       // per-query (lane-scalar)

    const char* Fb  = (const char*)(F + (size_t)b * 4096 * 256);
    const char* Hbb = (const char*)(Hb + (size_t)b * 256 * 4096);

    // per-lane pre-swizzled stage source offsets (dest is linear)
    int ksrc[2], vsrc[2];
#pragma unroll
    for (int t = 0; t < 2; ++t) {
        int d = (w * 2 + t) * 1024 + lane * 16;
        int row = d >> 9, col = d & 511;
        ksrc[t] = row * 512 + (col ^ ((row & 7) << 4));
        int c = d >> 5, kb2 = d & 31;
        vsrc[t] = c * 8192 + kb2;
    }

#define STAGE(bufn, I0)                                                         \
    do {                                                                        \
        const char* kb_ = Fb + (size_t)(I0) * 512;                              \
        const char* vb_ = Hbb + (size_t)(I0) * 2;                               \
        char* kl = (char*)Kd[bufn];                                             \
        char* vl = (char*)Vd[bufn];                                             \
        _Pragma("unroll") for (int t = 0; t < 2; ++t)                           \
            gload16(kb_ + ksrc[t], kl + (w * 2 + t) * 1024);                    \
        _Pragma("unroll") for (int t = 0; t < 2; ++t)                           \
            gload16(vb_ + vsrc[t], vl + (w * 2 + t) * 1024);                    \
    } while (0)

    int i0beg = ks * 1024;
    STAGE(0, i0beg);   // prologue
    __syncthreads();   // drains vmcnt(0): tile 0 ready

    for (int it = 0; it < 64; ++it) {
        int cur = it & 1;
        if (it + 1 < 64) STAGE(cur ^ 1, i0beg + (it + 1) * 16);  // fly under compute

        const char* Kl = (const char*)Kd[cur];
        const u16* Vl = Vd[cur];

        // ---- QK^T swapped: A = K (rows = keys), B = Q (regs).
        // s0[q] = S[key 4g+q][query r]
        f32x4 s0 = {0.f, 0.f, 0.f, 0.f};
        __builtin_amdgcn_s_setprio(1);
        {
            const char* kr = Kl + r * 512;
            int sw = (r & 7) << 4;
#pragma unroll
            for (int k = 0; k < 8; ++k) {
                f16x8 ka = *reinterpret_cast<const f16x8*>(kr + ((k * 64 + 16 * g) ^ sw));
                s0 = MFMA16(ka, Qf[k], s0);
            }
        }
        __builtin_amdgcn_s_setprio(0);

        // ---- softmax: lane holds 4 scores of query r; reduce over g-lanes via shfl ----
        float v = fmaxf(fmaxf(s0[0], s0[1]), fmaxf(s0[2], s0[3]));
        v = fmaxf(v, __shfl_xor(v, 16));
        v = fmaxf(v, __shfl_xor(v, 32));
        float grow = v - m;
        if (__all(grow <= 8.0f)) {  // T13 defer-max: skip rescale
#pragma unroll
            for (int q = 0; q < 4; ++q) s0[q] = exp2f((s0[q] - m) * L2E);
            float rs = (s0[0] + s0[1]) + (s0[2] + s0[3]);
            rs += __shfl_xor(rs, 16);
            rs += __shfl_xor(rs, 32);
            l += rs;
        } else {
            float mn = fmaxf(m, v);
            float corr = exp2f((m - mn) * L2E);
            m = mn;
#pragma unroll
            for (int q = 0; q < 4; ++q) s0[q] = exp2f((s0[q] - m) * L2E);
            float rs = (s0[0] + s0[1]) + (s0[2] + s0[3]);
            rs += __shfl_xor(rs, 16);
            rs += __shfl_xor(rs, 32);
            l = l * corr + rs;
#pragma unroll
            for (int ct = 0; ct < 16; ++ct) O[ct] *= corr;  // whole lane = one query
        }

        // ---- P -> PV B-frag: LANE-LOCAL by construction of 16x16x16 layout ----
        union { u32 wd[2]; f16x4 fr; } pb;
        pb.wd[0] = cvtpk(s0[0], s0[1]);
        pb.wd[1] = cvtpk(s0[2], s0[3]);

        // ---- PV (16x16x16): O[c][j] += V[c][k] * P[k][j]; A = V b64 reads ----
        __builtin_amdgcn_s_setprio(1);
#pragma unroll
        for (int ct = 0; ct < 16; ++ct) {
            f16x4 va = *reinterpret_cast<const f16x4*>(Vl + (ct * 16 + r) * 16 + 4 * g);
            O[ct] = MFMA16S(va, pb.fr, O[ct]);
        }
        __builtin_amdgcn_s_setprio(0);

        __syncthreads();  // drains vmcnt (next tile landed during compute); buffer reuse safe
    }
#undef STAGE

    // ---- normalize (lane-scalar) + packed store: O[ct][q] -> channel ct*16+4g+q ----
    float inv = 1.f / l;
    size_t mrow = (size_t)ks * 16384 + b * 4096 + j0 + r;
#pragma unroll
    for (int ct = 0; ct < 16; ++ct) {
        short4v pk;
#pragma unroll
        for (int q = 0; q < 4; ++q) pk[q] = (short)h16(O[ct][q] * inv);
        *reinterpret_cast<short4v*>(OP + mrow * 256 + ct * 16 + 4 * g) = pk;
    }
    if (g == 0) {
        size_t mi = mrow * 2;
        ML[mi] = m;
        ML[mi + 1] = l;
    }
}

// ---------------- merge key-splits (x4, normalized partials) -> OT fp16 [m][c] ----------------
__global__ __launch_bounds__(256) void k_merge(
    const u16* __restrict__ OP, const float* __restrict__ ML, u16* __restrict__ OT) {
    int t = blockIdx.x * 256 + threadIdx.x;  // 524288 threads
    int m = t >> 5;
    int c0 = (t & 31) * 8;
    const float L2E = 1.4426950408889634f;
    float mm[4], ll[4];
    float M = -1e30f;
#pragma unroll
    for (int ks = 0; ks < 4; ++ks) {
        size_t mi = ((size_t)ks * 16384 + m) * 2;
        mm[ks] = ML[mi];
        ll[ks] = ML[mi + 1];
        M = fmaxf(M, mm[ks]);
    }
    float wl[4], L = 0.f;
#pragma unroll
    for (int ks = 0; ks < 4; ++ks) {
        wl[ks] = exp2f((mm[ks] - M) * L2E) * ll[ks];
        L += wl[ks];
    }
    float inv = 1.f / L;
    float acc[8];
#pragma unroll
    for (int j = 0; j < 8; ++j) acc[j] = 0.f;
#pragma unroll
    for (int ks = 0; ks < 4; ++ks) {
        f16x8 v = ldh8(OP + ((size_t)ks * 16384 + m) * 256 + c0);
#pragma unroll
        for (int j = 0; j < 8; ++j) acc[j] += wl[ks] * (float)v[j];
    }
    short8 outp;
#pragma unroll
    for (int j = 0; j < 8; ++j) outp[j] = (short)h16(acc[j] * inv);
    *reinterpret_cast<short8*>(OT + (size_t)m * 256 + c0) = outp;
}

// ---------------- final conv: fp16 MFMA, f32 out ----------------
__global__ __launch_bounds__(256) void k_conv_out(
    const u16* __restrict__ WVB, const u16* __restrict__ OT,
    const float* __restrict__ bv, float* __restrict__ out) {
    int bidn = blockIdx.x & 255, bido = blockIdx.x >> 8;
    int w = threadIdx.x >> 6, lane = threadIdx.x & 63, r = lane & 15, g = lane >> 4;
    int o0 = bido * 64 + w * 16, n0 = bidn * 64;
    f32x4 acc[4];
#pragma unroll
    for (int i = 0; i < 4; ++i) acc[i] = {0.f, 0.f, 0.f, 0.f};
    const u16* arow = WVB + (size_t)(o0 + r) * 256;
#pragma unroll
    for (int ks = 0; ks < 8; ++ks) {
        int k0 = ks * 32 + 8 * g;
        f16x8 a = ldh8(arow + k0);
#pragma unroll
        for (int ntl = 0; ntl < 4; ++ntl) {
            f16x8 bb = ldh8(OT + (size_t)(n0 + ntl * 16 + r) * 256 + k0);
            acc[ntl] = MFMA16(a, bb, acc[ntl]);
        }
    }
#pragma unroll
    for (int ntl = 0; ntl < 4; ++ntl) {
#pragma unroll
        for (int q = 0; q < 4; ++q) {
            int o = o0 + 4 * g + q;
            int nf = n0 + ntl * 16 + r;
            int bb = nf >> 12, n = nf & 4095;
            out[((size_t)(bb * 256 + o)) * 4096 + n] = acc[ntl][q] + bv[o];
        }
    }
}

extern "C" void kernel_launch(void* const* d_in, const int* in_sizes, int n_in,
                              void* d_out, int out_size, void* d_ws, size_t ws_size,
                              hipStream_t stream) {
    const float* x  = (const float*)d_in[0];
    const float* Wf = (const float*)d_in[1];
    const float* bf = (const float*)d_in[2];
    const float* Wg = (const float*)d_in[3];
    const float* bg = (const float*)d_in[4];
    const float* Wh = (const float*)d_in[5];
    const float* bh = (const float*)d_in[6];
    const float* Wv = (const float*)d_in[7];
    const float* bv = (const float*)d_in[8];
    float* out = (float*)d_out;
    char* ws = (char*)d_ws;

    u16* WFH = (u16*)(ws + OFF_WFH);
    u16* WFL = (u16*)(ws + OFF_WFL);
    u16* WGH = (u16*)(ws + OFF_WGH);
    u16* WGL = (u16*)(ws + OFF_WGL);
    u16* WHB = (u16*)(ws + OFF_WHB);
    u16* WVB = (u16*)(ws + OFF_WVB);
    float* ML = (float*)(ws + OFF_ML);
    u16* F   = (u16*)(ws + OFF_F);
    u16* G   = (u16*)(ws + OFF_G);
    u16* H   = (u16*)(ws + OFF_H);
    u16* XTH = (u16*)(ws + OFF_XTH);
    u16* XTL = (u16*)(ws + OFF_XTL);
    u16* OP  = (u16*)(ws + OFF_OP);   // aliases Xt (dead after convs)
    u16* OT  = (u16*)(ws + OFF_OT);   // aliases F (dead after attn)

    k_prep_w<<<256, 256, 0, stream>>>(Wf, Wg, Wh, Wv, WFH, WFL, WGH, WGL, WHB, WVB);
    k_prep_x<<<1024, 256, 0, stream>>>(x, XTH, XTL);
    k_conv_fg<<<1024, 256, 0, stream>>>(XTH, XTL, WFH, WFL, WGH, WGL, bf, bg, F, G);
    k_conv_h<<<1024, 256, 0, stream>>>(WHB, XTH, bh, H);
    k_attn<<<1024, 256, 0, stream>>>(F, G, H, OP, ML);
    k_merge<<<2048, 256, 0, stream>>>(OP, ML, OT);
    k_conv_out<<<1024, 256, 0, stream>>>(WVB, OT, bv, out);
}

// Round 14
// 217.267 us; speedup vs baseline: 4.7184x; 2.2140x over previous
//
#include <hip/hip_runtime.h>
#include <hip/hip_bf16.h>

// SAGAN attention block: B=4, C=256, H=W=64 (N=4096).
// Round 14: k_attn / k_conv_h(key-permuted) / k_merge / k_conv_out reverted
// byte-for-byte to round 10 (proven: attn 138us, absmax 0.0078). The round's
// change is the INPUT pipeline: x stored once as fp16 Xt[m][c]; conv_fg and
// conv_h are single-pass fp16 MFMA (bf16 hi/lo 3-pass machinery deleted --
// fp16's 11-bit mantissa gives delta-f ~1e-3, same order as the fp16 storage
// error already present). prep_x writes half the bytes; conv_fg does 1/3 the
// MFMAs and 1/4 the loads. r13 lesson confirmed again: occupancy lever is
// register-blocked (O 64 + Qf 32 + temps > 170/3-wave budget); don't fight it.

typedef short short8 __attribute__((ext_vector_type(8)));
typedef short short4v __attribute__((ext_vector_type(4)));
typedef float f32x4 __attribute__((ext_vector_type(4)));
typedef _Float16 f16x8 __attribute__((ext_vector_type(8)));
typedef unsigned short u16;
typedef unsigned int u32;

#define DEV static __device__ __forceinline__
#define MFMA16(a, b, c) __builtin_amdgcn_mfma_f32_16x16x32_f16(a, b, c, 0, 0, 0)

DEV u16 h16(float x) {
    union { _Float16 h; u16 u; } c;
    c.h = (_Float16)x;
    return c.u;
}
DEV f16x8 ldh8(const u16* p) { return *reinterpret_cast<const f16x8*>(p); }

DEV u32 cvtpk(float a, float b) {  // packed f16 (rtz): lo=a, hi=b
    u32 r;
    asm("v_cvt_pkrtz_f16_f32 %0, %1, %2" : "=v"(r) : "v"(a), "v"(b));
    return r;
}

// async global->LDS, 16B per lane; dst is wave-uniform base, HW adds lane*16
DEV void gload16(const void* g, void* l) {
    __builtin_amdgcn_global_load_lds(
        (const __attribute__((address_space(1))) unsigned int*)g,
        (__attribute__((address_space(3))) unsigned int*)l, 16, 0, 0);
}

// ---- workspace byte offsets ----
constexpr size_t OFF_WF = 0;          // 128K fp16
constexpr size_t OFF_WG = 131072;
constexpr size_t OFF_WH = 262144;
constexpr size_t OFF_WV = 393216;
constexpr size_t OFF_ML = 524288;     // 256K f32 pairs (2 splits x 16384 x {m,l})
constexpr size_t OFF_F  = 1310720;    // 8M fp16 [m][c]   (K source)
constexpr size_t OFF_G  = OFF_F + 8388608;    // 8M fp16 [m][c]  (Q source)
constexpr size_t OFF_H  = OFF_G + 8388608;    // 8M fp16 [b][c][n] (V, keys permuted per 32-block)
constexpr size_t OFF_XT = OFF_H + 8388608;    // 8M fp16 [m][c], dead after convs
constexpr size_t OFF_OP = OFF_XT;             // 16M fp16 (2 splits), aliases dead Xt + 8M fresh
constexpr size_t OFF_OT = OFF_F;              // 8M fp16, aliases dead F
// high-water mark = OFF_OP + 16777216 = 43,253,760 bytes (well under proven 60M)

// ---------------- weight prep: all fp16 ----------------
__global__ __launch_bounds__(256) void k_prep_w(
    const float* __restrict__ Wf, const float* __restrict__ Wg,
    const float* __restrict__ Wh, const float* __restrict__ Wv,
    u16* WF, u16* WG, u16* WH, u16* WV) {
    int i = blockIdx.x * 256 + threadIdx.x;
    WF[i] = h16(Wf[i]);
    WG[i] = h16(Wg[i]);
    WH[i] = h16(Wh[i]);
    WV[i] = h16(Wv[i]);
}

// ---------------- x transpose: x[b][c][n] f32 -> Xt[b][n][c] fp16 ----------------
__global__ __launch_bounds__(256) void k_prep_x(const float* __restrict__ x, u16* Xt) {
    __shared__ float lds[64][65];
    int bid = blockIdx.x;                 // 1024 blocks: b(4) x ctile(4) x ntile(64)
    int b = bid >> 8, rem = bid & 255, ct = rem >> 6, nt = rem & 63;
    int tid = threadIdx.x;
    int tx = tid & 63, ty = tid >> 6;
    const float* src = x + ((size_t)(b * 256 + ct * 64)) * 4096 + nt * 64;
#pragma unroll
    for (int k = 0; k < 16; ++k) {
        int cl = ty * 16 + k;
        lds[cl][tx] = src[(size_t)cl * 4096 + tx];
    }
    __syncthreads();
    int nl = tid >> 2, cg = tid & 3;
    short8 h0, h1;
#pragma unroll
    for (int j = 0; j < 8; ++j) h0[j] = (short)h16(lds[cg * 16 + j][nl]);
#pragma unroll
    for (int j = 8; j < 16; ++j) h1[j - 8] = (short)h16(lds[cg * 16 + j][nl]);
    size_t dst = ((size_t)(b * 4096 + nt * 64 + nl)) * 256 + ct * 64 + cg * 16;
    *reinterpret_cast<short8*>(Xt + dst) = h0;
    *reinterpret_cast<short8*>(Xt + dst + 8) = h1;
}

// ---------------- conv f,g: single-pass fp16 MFMA, fp16 out ----------------
__global__ __launch_bounds__(256) void k_conv_fg(
    const u16* __restrict__ Xt, const u16* __restrict__ WF, const u16* __restrict__ WG,
    const float* __restrict__ bf, const float* __restrict__ bg,
    u16* F, u16* G) {
    int bidm = blockIdx.x & 255, bido = blockIdx.x >> 8;
    int w = threadIdx.x >> 6, lane = threadIdx.x & 63, r = lane & 15, g = lane >> 4;
    int m0 = bidm * 64 + w * 16, o0 = bido * 64;
    f32x4 fa[4], ga[4];
#pragma unroll
    for (int i = 0; i < 4; ++i) { fa[i] = {0.f, 0.f, 0.f, 0.f}; ga[i] = {0.f, 0.f, 0.f, 0.f}; }
    const u16* ar = Xt + (size_t)(m0 + r) * 256;
#pragma unroll
    for (int ks = 0; ks < 8; ++ks) {
        int k0 = ks * 32 + 8 * g;
        f16x8 a = ldh8(ar + k0);
#pragma unroll
        for (int ot = 0; ot < 4; ++ot) {
            size_t wrow = (size_t)(o0 + ot * 16 + r) * 256 + k0;
            fa[ot] = MFMA16(a, ldh8(WF + wrow), fa[ot]);
            ga[ot] = MFMA16(a, ldh8(WG + wrow), ga[ot]);
        }
    }
#pragma unroll
    for (int ot = 0; ot < 4; ++ot) {
#pragma unroll
        for (int q = 0; q < 4; ++q) {
            int row = m0 + 4 * g + q;
            int col = o0 + ot * 16 + r;
            size_t idx = (size_t)row * 256 + col;
            F[idx] = h16(fa[ot][q] + bf[col]);
            G[idx] = h16(ga[ot][q] + bg[col]);
        }
    }
}

// ---------------- conv h: fp16 MFMA, fp16 out, [b][c][n], keys permuted per 32-block ----------------
__global__ __launch_bounds__(256) void k_conv_h(
    const u16* __restrict__ WH, const u16* __restrict__ Xt,
    const float* __restrict__ bh, u16* Hb) {
    int bidn = blockIdx.x & 255, bido = blockIdx.x >> 8;
    int w = threadIdx.x >> 6, lane = threadIdx.x & 63, r = lane & 15, g = lane >> 4;
    int o0 = bido * 64 + w * 16, n0 = bidn * 64;
    f32x4 acc[4];
#pragma unroll
    for (int i = 0; i < 4; ++i) acc[i] = {0.f, 0.f, 0.f, 0.f};
    const u16* arow = WH + (size_t)(o0 + r) * 256;
#pragma unroll
    for (int ks = 0; ks < 8; ++ks) {
        int k0 = ks * 32 + 8 * g;
        f16x8 a = ldh8(arow + k0);
#pragma unroll
        for (int ntl = 0; ntl < 4; ++ntl) {
            f16x8 bb = ldh8(Xt + (size_t)(n0 + ntl * 16 + r) * 256 + k0);
            acc[ntl] = MFMA16(a, bb, acc[ntl]);
        }
    }
#pragma unroll
    for (int ntl = 0; ntl < 4; ++ntl) {
#pragma unroll
        for (int q = 0; q < 4; ++q) {
            int o = o0 + 4 * g + q;
            int nf = n0 + ntl * 16 + r;
            int bb = nf >> 12, n = nf & 4095;
            // permute key within its 32-block: slot kinv(k) holds key k, so the
            // attention PV B-fragment (slots 8g+j) is lane-local after swapped QK.
            int k5 = n & 31;
            int kp = (k5 < 16) ? (8 * (k5 >> 2) + (k5 & 3))
                               : (8 * ((k5 - 16) >> 2) + 4 + (k5 & 3));
            int np = (n & ~31) | kp;
            Hb[((size_t)(bb * 256 + o)) * 4096 + np] = h16(acc[ntl][q] + bh[o]);
        }
    }
}

// ---------------- flash attention: r10 verbatim (swapped-QK 16x16, lane-local P) ----------------
__global__ __launch_bounds__(256, 2) void k_attn(
    const u16* __restrict__ F, const u16* __restrict__ G,
    const u16* __restrict__ Hb, u16* __restrict__ OP, float* __restrict__ ML) {
    // K tile [32 keys][256 c] fp16, 16KB each, swizzle byte ^= (row&7)<<4.
    // V tile paired-row: byte(c,s) = (c>>1)*128 + ((s*2 + (c&1)*64) ^ (((c>>1)&7)<<4)),
    // where slot s holds key kappa(s) (permutation baked into H by conv_h).
    __shared__ u16 Kd[2][8192];
    __shared__ u16 Vd[2][8192];

    int bid = blockIdx.x;            // 512 = 8 xcd * 64; 2 blocks/CU
    int xcd = bid & 7, idx = bid >> 3;
    int b = xcd >> 1, ks = xcd & 1;  // XCD carries (batch, key-half)
    int tid = threadIdx.x;
    int w = tid >> 6, lane = tid & 63, r = lane & 15, g = lane >> 4;
    int j0 = idx * 64 + w * 16;      // wave's 16 queries
    const float L2E = 1.4426950408889634f;

    // Q as QK B-operand (col = query r): Qf[k] = Q[j0+r][k*32 + 8g .. +7]
    f16x8 Qf[8];
    {
        const u16* q = G + (size_t)(b * 4096 + j0 + r) * 256;
#pragma unroll
        for (int k = 0; k < 8; ++k) Qf[k] = ldh8(q + k * 32 + 8 * g);
    }
    // O[ct][q] = O[channel ct*16 + 4g + q][query j0 + r]  (PV D-layout, col = query)
    f32x4 O[16];
#pragma unroll
    for (int i = 0; i < 16; ++i) O[i] = {0.f, 0.f, 0.f, 0.f};
    float m = -1e30f, l = 0.f;       // per-query (lane-scalar)

    const char* Fb  = (const char*)(F + (size_t)b * 4096 * 256);
    const char* Hbb = (const char*)(Hb + (size_t)b * 256 * 4096);

    // per-lane pre-swizzled stage source offsets (dest is linear)
    int ksrc[4], vsrc[4];
#pragma unroll
    for (int t = 0; t < 4; ++t) {
        int d = (w * 4 + t) * 1024 + lane * 16;
        int row = d >> 9, col = d & 511;
        ksrc[t] = row * 512 + (col ^ ((row & 7) << 4));
        int r128 = d >> 7, wn = d & 127;
        int wp = wn ^ ((r128 & 7) << 4);
        vsrc[t] = ((r128 * 2 + (wp >> 6)) << 13) + (wp & 63);
    }

#define STAGE(bufn, I0)                                                         \
    do {                                                                        \
        const char* kb_ = Fb + (size_t)(I0) * 512;                              \
        const char* vb_ = Hbb + (size_t)(I0) * 2;                               \
        char* kl = (char*)Kd[bufn];                                             \
        char* vl = (char*)Vd[bufn];                                             \
        _Pragma("unroll") for (int t = 0; t < 4; ++t)                           \
            gload16(kb_ + ksrc[t], kl + (w * 4 + t) * 1024);                    \
        _Pragma("unroll") for (int t = 0; t < 4; ++t)                           \
            gload16(vb_ + vsrc[t], vl + (w * 4 + t) * 1024);                    \
    } while (0)

    int i0beg = ks * 2048;
    STAGE(0, i0beg);   // prologue
    __syncthreads();   // drains vmcnt(0): tile 0 ready

    for (int it = 0; it < 64; ++it) {
        int cur = it & 1;
        if (it + 1 < 64) STAGE(cur ^ 1, i0beg + (it + 1) * 32);  // fly under compute

        const char* Kl = (const char*)Kd[cur];
        const char* Vl = (const char*)Vd[cur];

        // ---- QK^T swapped: A = K (rows = keys), B = Q.
        // s0[q] = S[key 4g+q][query r], s1[q] = S[key 16+4g+q][query r]
        f32x4 s0 = {0.f, 0.f, 0.f, 0.f};
        f32x4 s1 = {0.f, 0.f, 0.f, 0.f};
        __builtin_amdgcn_s_setprio(1);
        {
            const char* kr = Kl + r * 512;
            int sw = (r & 7) << 4;
#pragma unroll
            for (int k = 0; k < 8; ++k) {
                f16x8 ka = *reinterpret_cast<const f16x8*>(kr + ((k * 64 + 16 * g) ^ sw));
                s0 = MFMA16(ka, Qf[k], s0);
            }
        }
        {
            const char* kr = Kl + (16 + r) * 512;
            int sw = (r & 7) << 4;  // (16+r)&7 == r&7
#pragma unroll
            for (int k = 0; k < 8; ++k) {
                f16x8 ka = *reinterpret_cast<const f16x8*>(kr + ((k * 64 + 16 * g) ^ sw));
                s1 = MFMA16(ka, Qf[k], s1);
            }
        }
        __builtin_amdgcn_s_setprio(0);

        // ---- softmax: lane holds 8 scores of query r; reduce over g-lanes via shfl ----
        float v = fmaxf(fmaxf(fmaxf(s0[0], s0[1]), fmaxf(s0[2], s0[3])),
                        fmaxf(fmaxf(s1[0], s1[1]), fmaxf(s1[2], s1[3])));
        v = fmaxf(v, __shfl_xor(v, 16));
        v = fmaxf(v, __shfl_xor(v, 32));
        float grow = v - m;
        if (__all(grow <= 8.0f)) {  // T13 defer-max: skip rescale
#pragma unroll
            for (int q = 0; q < 4; ++q) {
                s0[q] = exp2f((s0[q] - m) * L2E);
                s1[q] = exp2f((s1[q] - m) * L2E);
            }
            float rs = (s0[0] + s0[1] + s0[2] + s0[3]) + (s1[0] + s1[1] + s1[2] + s1[3]);
            rs += __shfl_xor(rs, 16);
            rs += __shfl_xor(rs, 32);
            l += rs;
        } else {
            float mn = fmaxf(m, v);
            float corr = exp2f((m - mn) * L2E);
            m = mn;
#pragma unroll
            for (int q = 0; q < 4; ++q) {
                s0[q] = exp2f((s0[q] - m) * L2E);
                s1[q] = exp2f((s1[q] - m) * L2E);
            }
            float rs = (s0[0] + s0[1] + s0[2] + s0[3]) + (s1[0] + s1[1] + s1[2] + s1[3]);
            rs += __shfl_xor(rs, 16);
            rs += __shfl_xor(rs, 32);
            l = l * corr + rs;
#pragma unroll
            for (int ct = 0; ct < 16; ++ct) O[ct] *= corr;  // whole lane = one query
        }

        // ---- P -> PV B-frag: LANE-LOCAL (V keys permuted so slot 8g+j = key kappa) ----
        union { u32 wd[4]; f16x8 fr; } pu;
        pu.wd[0] = cvtpk(s0[0], s0[1]);
        pu.wd[1] = cvtpk(s0[2], s0[3]);
        pu.wd[2] = cvtpk(s1[0], s1[1]);
        pu.wd[3] = cvtpk(s1[2], s1[3]);

        // ---- PV: O[c][j] += V[c][slot] * P[slot][j]; A = V paired-row reads ----
        __builtin_amdgcn_s_setprio(1);
#pragma unroll
        for (int ct = 0; ct < 16; ++ct) {
            int c = ct * 16 + r;
            const char* vr = Vl + (c >> 1) * 128;
            int swv = ((c >> 1) & 7) << 4;
            int cb = (c & 1) * 64;
            f16x8 vb = *reinterpret_cast<const f16x8*>(vr + ((16 * g + cb) ^ swv));
            O[ct] = MFMA16(vb, pu.fr, O[ct]);
        }
        __builtin_amdgcn_s_setprio(0);

        __syncthreads();  // drains vmcnt (next tile landed during compute); buffer reuse safe
    }
#undef STAGE

    // ---- normalize (lane-scalar) + packed store: O[ct][q] -> channel ct*16+4g+q ----
    float inv = 1.f / l;
    size_t mrow = (size_t)ks * 16384 + b * 4096 + j0 + r;
#pragma unroll
    for (int ct = 0; ct < 16; ++ct) {
        short4v pk;
#pragma unroll
        for (int q = 0; q < 4; ++q) pk[q] = (short)h16(O[ct][q] * inv);
        *reinterpret_cast<short4v*>(OP + mrow * 256 + ct * 16 + 4 * g) = pk;
    }
    if (g == 0) {
        size_t mi = mrow * 2;
        ML[mi] = m;
        ML[mi + 1] = l;
    }
}

// ---------------- merge key-splits (x2, normalized partials) -> OT fp16 [m][c] ----------------
__global__ __launch_bounds__(256) void k_merge(
    const u16* __restrict__ OP, const float* __restrict__ ML, u16* __restrict__ OT) {
    int t = blockIdx.x * 256 + threadIdx.x;  // 524288 threads
    int m = t >> 5;
    int c0 = (t & 31) * 8;
    const float L2E = 1.4426950408889634f;
    float m0 = ML[(size_t)m * 2], l0 = ML[(size_t)m * 2 + 1];
    float m1 = ML[((size_t)16384 + m) * 2], l1 = ML[((size_t)16384 + m) * 2 + 1];
    float M = fmaxf(m0, m1);
    float wl0 = exp2f((m0 - M) * L2E) * l0;
    float wl1 = exp2f((m1 - M) * L2E) * l1;
    float inv = 1.f / (wl0 + wl1);
    f16x8 v0 = ldh8(OP + (size_t)m * 256 + c0);
    f16x8 v1 = ldh8(OP + ((size_t)16384 + m) * 256 + c0);
    short8 outp;
#pragma unroll
    for (int j = 0; j < 8; ++j)
        outp[j] = (short)h16((wl0 * (float)v0[j] + wl1 * (float)v1[j]) * inv);
    *reinterpret_cast<short8*>(OT + (size_t)m * 256 + c0) = outp;
}

// ---------------- final conv: fp16 MFMA, f32 out ----------------
__global__ __launch_bounds__(256) void k_conv_out(
    const u16* __restrict__ WV, const u16* __restrict__ OT,
    const float* __restrict__ bv, float* __restrict__ out) {
    int bidn = blockIdx.x & 255, bido = blockIdx.x >> 8;
    int w = threadIdx.x >> 6, lane = threadIdx.x & 63, r = lane & 15, g = lane >> 4;
    int o0 = bido * 64 + w * 16, n0 = bidn * 64;
    f32x4 acc[4];
#pragma unroll
    for (int i = 0; i < 4; ++i) acc[i] = {0.f, 0.f, 0.f, 0.f};
    const u16* arow = WV + (size_t)(o0 + r) * 256;
#pragma unroll
    for (int ks = 0; ks < 8; ++ks) {
        int k0 = ks * 32 + 8 * g;
        f16x8 a = ldh8(arow + k0);
#pragma unroll
        for (int ntl = 0; ntl < 4; ++ntl) {
            f16x8 bb = ldh8(OT + (size_t)(n0 + ntl * 16 + r) * 256 + k0);
            acc[ntl] = MFMA16(a, bb, acc[ntl]);
        }
    }
#pragma unroll
    for (int ntl = 0; ntl < 4; ++ntl) {
#pragma unroll
        for (int q = 0; q < 4; ++q) {
            int o = o0 + 4 * g + q;
            int nf = n0 + ntl * 16 + r;
            int bb = nf >> 12, n = nf & 4095;
            out[((size_t)(bb * 256 + o)) * 4096 + n] = acc[ntl][q] + bv[o];
        }
    }
}

extern "C" void kernel_launch(void* const* d_in, const int* in_sizes, int n_in,
                              void* d_out, int out_size, void* d_ws, size_t ws_size,
                              hipStream_t stream) {
    const float* x  = (const float*)d_in[0];
    const float* Wf = (const float*)d_in[1];
    const float* bf = (const float*)d_in[2];
    const float* Wg = (const float*)d_in[3];
    const float* bg = (const float*)d_in[4];
    const float* Wh = (const float*)d_in[5];
    const float* bh = (const float*)d_in[6];
    const float* Wv = (const float*)d_in[7];
    const float* bv = (const float*)d_in[8];
    float* out = (float*)d_out;
    char* ws = (char*)d_ws;

    u16* WF = (u16*)(ws + OFF_WF);
    u16* WG = (u16*)(ws + OFF_WG);
    u16* WH = (u16*)(ws + OFF_WH);
    u16* WV = (u16*)(ws + OFF_WV);
    float* ML = (float*)(ws + OFF_ML);
    u16* F  = (u16*)(ws + OFF_F);
    u16* G  = (u16*)(ws + OFF_G);
    u16* H  = (u16*)(ws + OFF_H);
    u16* XT = (u16*)(ws + OFF_XT);
    u16* OP = (u16*)(ws + OFF_OP);   // aliases XT (dead after convs)
    u16* OT = (u16*)(ws + OFF_OT);   // aliases F (dead after attn)

    k_prep_w<<<256, 256, 0, stream>>>(Wf, Wg, Wh, Wv, WF, WG, WH, WV);
    k_prep_x<<<1024, 256, 0, stream>>>(x, XT);
    k_conv_fg<<<1024, 256, 0, stream>>>(XT, WF, WG, bf, bg, F, G);
    k_conv_h<<<1024, 256, 0, stream>>>(WH, XT, bh, H);
    k_attn<<<512, 256, 0, stream>>>(F, G, H, OP, ML);
    k_merge<<<2048, 256, 0, stream>>>(OP, ML, OT);
    k_conv_out<<<1024, 256, 0, stream>>>(WV, OT, bv, out);
}

// Round 16
// 213.953 us; speedup vs baseline: 4.7915x; 1.0155x over previous
//
#include <hip/hip_runtime.h>
#include <hip/hip_bf16.h>

// SAGAN attention block: B=4, C=256, H=W=64 (N=4096).
// Round 16 = r14 k_attn + ONLY the two verified r15 deltas:
//  - defer-sum: l lane-partial, reduced across g-lanes once at the end
//    (exact: corr is wave-consistent per query; removes 128 shfl/iter-loop)
//  - V read base precompute (proved byte-identity; ct*1024 immediates)
// K reads byte-identical to r14 (r15's Qf slice-permute was WRONG: b6 varies
// per lane, but MFMA pairs A-chunk(b6(row)) with B-chunk(b6(col)) across
// lanes -> mismatched contractions for half the (row,col) pairs).
// r14 baseline: attn 138us, total 217us, absmax 0.0078.

typedef short short8 __attribute__((ext_vector_type(8)));
typedef short short4v __attribute__((ext_vector_type(4)));
typedef float f32x4 __attribute__((ext_vector_type(4)));
typedef _Float16 f16x8 __attribute__((ext_vector_type(8)));
typedef unsigned short u16;
typedef unsigned int u32;

#define DEV static __device__ __forceinline__
#define MFMA16(a, b, c) __builtin_amdgcn_mfma_f32_16x16x32_f16(a, b, c, 0, 0, 0)

DEV u16 h16(float x) {
    union { _Float16 h; u16 u; } c;
    c.h = (_Float16)x;
    return c.u;
}
DEV f16x8 ldh8(const u16* p) { return *reinterpret_cast<const f16x8*>(p); }

DEV u32 cvtpk(float a, float b) {  // packed f16 (rtz): lo=a, hi=b
    u32 r;
    asm("v_cvt_pkrtz_f16_f32 %0, %1, %2" : "=v"(r) : "v"(a), "v"(b));
    return r;
}

// async global->LDS, 16B per lane; dst is wave-uniform base, HW adds lane*16
DEV void gload16(const void* g, void* l) {
    __builtin_amdgcn_global_load_lds(
        (const __attribute__((address_space(1))) unsigned int*)g,
        (__attribute__((address_space(3))) unsigned int*)l, 16, 0, 0);
}

// ---- workspace byte offsets ----
constexpr size_t OFF_WF = 0;          // 128K fp16
constexpr size_t OFF_WG = 131072;
constexpr size_t OFF_WH = 262144;
constexpr size_t OFF_WV = 393216;
constexpr size_t OFF_ML = 524288;     // 256K f32 pairs (2 splits x 16384 x {m,l})
constexpr size_t OFF_F  = 1310720;    // 8M fp16 [m][c]   (K source)
constexpr size_t OFF_G  = OFF_F + 8388608;    // 8M fp16 [m][c]  (Q source)
constexpr size_t OFF_H  = OFF_G + 8388608;    // 8M fp16 [b][c][n] (V, keys permuted per 32-block)
constexpr size_t OFF_XT = OFF_H + 8388608;    // 8M fp16 [m][c], dead after convs
constexpr size_t OFF_OP = OFF_XT;             // 16M fp16 (2 splits), aliases dead Xt + 8M fresh
constexpr size_t OFF_OT = OFF_F;              // 8M fp16, aliases dead F
// high-water mark = OFF_OP + 16777216 = 43,253,760 bytes

// ---------------- weight prep: all fp16 ----------------
__global__ __launch_bounds__(256) void k_prep_w(
    const float* __restrict__ Wf, const float* __restrict__ Wg,
    const float* __restrict__ Wh, const float* __restrict__ Wv,
    u16* WF, u16* WG, u16* WH, u16* WV) {
    int i = blockIdx.x * 256 + threadIdx.x;
    WF[i] = h16(Wf[i]);
    WG[i] = h16(Wg[i]);
    WH[i] = h16(Wh[i]);
    WV[i] = h16(Wv[i]);
}

// ---------------- x transpose: x[b][c][n] f32 -> Xt[b][n][c] fp16 ----------------
__global__ __launch_bounds__(256) void k_prep_x(const float* __restrict__ x, u16* Xt) {
    __shared__ float lds[64][65];
    int bid = blockIdx.x;                 // 1024 blocks: b(4) x ctile(4) x ntile(64)
    int b = bid >> 8, rem = bid & 255, ct = rem >> 6, nt = rem & 63;
    int tid = threadIdx.x;
    int tx = tid & 63, ty = tid >> 6;
    const float* src = x + ((size_t)(b * 256 + ct * 64)) * 4096 + nt * 64;
#pragma unroll
    for (int k = 0; k < 16; ++k) {
        int cl = ty * 16 + k;
        lds[cl][tx] = src[(size_t)cl * 4096 + tx];
    }
    __syncthreads();
    int nl = tid >> 2, cg = tid & 3;
    short8 h0, h1;
#pragma unroll
    for (int j = 0; j < 8; ++j) h0[j] = (short)h16(lds[cg * 16 + j][nl]);
#pragma unroll
    for (int j = 8; j < 16; ++j) h1[j - 8] = (short)h16(lds[cg * 16 + j][nl]);
    size_t dst = ((size_t)(b * 4096 + nt * 64 + nl)) * 256 + ct * 64 + cg * 16;
    *reinterpret_cast<short8*>(Xt + dst) = h0;
    *reinterpret_cast<short8*>(Xt + dst + 8) = h1;
}

// ---------------- conv f,g: single-pass fp16 MFMA, fp16 out ----------------
__global__ __launch_bounds__(256) void k_conv_fg(
    const u16* __restrict__ Xt, const u16* __restrict__ WF, const u16* __restrict__ WG,
    const float* __restrict__ bf, const float* __restrict__ bg,
    u16* F, u16* G) {
    int bidm = blockIdx.x & 255, bido = blockIdx.x >> 8;
    int w = threadIdx.x >> 6, lane = threadIdx.x & 63, r = lane & 15, g = lane >> 4;
    int m0 = bidm * 64 + w * 16, o0 = bido * 64;
    f32x4 fa[4], ga[4];
#pragma unroll
    for (int i = 0; i < 4; ++i) { fa[i] = {0.f, 0.f, 0.f, 0.f}; ga[i] = {0.f, 0.f, 0.f, 0.f}; }
    const u16* ar = Xt + (size_t)(m0 + r) * 256;
#pragma unroll
    for (int ks = 0; ks < 8; ++ks) {
        int k0 = ks * 32 + 8 * g;
        f16x8 a = ldh8(ar + k0);
#pragma unroll
        for (int ot = 0; ot < 4; ++ot) {
            size_t wrow = (size_t)(o0 + ot * 16 + r) * 256 + k0;
            fa[ot] = MFMA16(a, ldh8(WF + wrow), fa[ot]);
            ga[ot] = MFMA16(a, ldh8(WG + wrow), ga[ot]);
        }
    }
#pragma unroll
    for (int ot = 0; ot < 4; ++ot) {
#pragma unroll
        for (int q = 0; q < 4; ++q) {
            int row = m0 + 4 * g + q;
            int col = o0 + ot * 16 + r;
            size_t idx = (size_t)row * 256 + col;
            F[idx] = h16(fa[ot][q] + bf[col]);
            G[idx] = h16(ga[ot][q] + bg[col]);
        }
    }
}

// ---------------- conv h: fp16 MFMA, fp16 out, [b][c][n], keys permuted per 32-block ----------------
__global__ __launch_bounds__(256) void k_conv_h(
    const u16* __restrict__ WH, const u16* __restrict__ Xt,
    const float* __restrict__ bh, u16* Hb) {
    int bidn = blockIdx.x & 255, bido = blockIdx.x >> 8;
    int w = threadIdx.x >> 6, lane = threadIdx.x & 63, r = lane & 15, g = lane >> 4;
    int o0 = bido * 64 + w * 16, n0 = bidn * 64;
    f32x4 acc[4];
#pragma unroll
    for (int i = 0; i < 4; ++i) acc[i] = {0.f, 0.f, 0.f, 0.f};
    const u16* arow = WH + (size_t)(o0 + r) * 256;
#pragma unroll
    for (int ks = 0; ks < 8; ++ks) {
        int k0 = ks * 32 + 8 * g;
        f16x8 a = ldh8(arow + k0);
#pragma unroll
        for (int ntl = 0; ntl < 4; ++ntl) {
            f16x8 bb = ldh8(Xt + (size_t)(n0 + ntl * 16 + r) * 256 + k0);
            acc[ntl] = MFMA16(a, bb, acc[ntl]);
        }
    }
#pragma unroll
    for (int ntl = 0; ntl < 4; ++ntl) {
#pragma unroll
        for (int q = 0; q < 4; ++q) {
            int o = o0 + 4 * g + q;
            int nf = n0 + ntl * 16 + r;
            int bb = nf >> 12, n = nf & 4095;
            // permute key within its 32-block: slot kinv(k) holds key k, so the
            // attention PV B-fragment (slots 8g+j) is lane-local after swapped QK.
            int k5 = n & 31;
            int kp = (k5 < 16) ? (8 * (k5 >> 2) + (k5 & 3))
                               : (8 * ((k5 - 16) >> 2) + 4 + (k5 & 3));
            int np = (n & ~31) | kp;
            Hb[((size_t)(bb * 256 + o)) * 4096 + np] = h16(acc[ntl][q] + bh[o]);
        }
    }
}

// ---------------- flash attention: swapped-QK 16x16, lane-local P, defer-sum ----------------
__global__ __launch_bounds__(256, 2) void k_attn(
    const u16* __restrict__ F, const u16* __restrict__ G,
    const u16* __restrict__ Hb, u16* __restrict__ OP, float* __restrict__ ML) {
    // K tile [32 keys][256 c] fp16, 16KB each, swizzle byte ^= (row&7)<<4.
    // V tile paired-row: byte(c,s) = (c>>1)*128 + ((s*2 + (c&1)*64) ^ (((c>>1)&7)<<4)),
    // slot s holds key kappa(s) (permutation baked into H by conv_h).
    __shared__ u16 Kd[2][8192];
    __shared__ u16 Vd[2][8192];

    int bid = blockIdx.x;            // 512 = 8 xcd * 64; 2 blocks/CU
    int xcd = bid & 7, idx = bid >> 3;
    int b = xcd >> 1, ks = xcd & 1;  // XCD carries (batch, key-half)
    int tid = threadIdx.x;
    int w = tid >> 6, lane = tid & 63, r = lane & 15, g = lane >> 4;
    int j0 = idx * 64 + w * 16;      // wave's 16 queries
    const float L2E = 1.4426950408889634f;

    // V lane-constant offset (ct part is ct*1024, an immediate) — exact identity:
    // c = ct*16 + r  =>  (c>>1)*128 = ct*1024 + (r>>1)*128; swv, cb lane-constant.
    int vlc = (r >> 1) * 128 + (((16 * g) + (r & 1) * 64) ^ (((r >> 1) & 7) << 4));

    // Q as QK B-operand (col = query r): Qf[k] = Q[j0+r][k*32 + 8g .. +7]
    f16x8 Qf[8];
    {
        const u16* q = G + (size_t)(b * 4096 + j0 + r) * 256;
#pragma unroll
        for (int k = 0; k < 8; ++k) Qf[k] = ldh8(q + k * 32 + 8 * g);
    }
    // O[ct][q] = O[channel ct*16 + 4g + q][query j0 + r]
    f32x4 O[16];
#pragma unroll
    for (int i = 0; i < 16; ++i) O[i] = {0.f, 0.f, 0.f, 0.f};
    float m = -1e30f, l = 0.f;       // m wave-consistent per query; l LANE-PARTIAL (defer-sum)

    const char* Fb  = (const char*)(F + (size_t)b * 4096 * 256);
    const char* Hbb = (const char*)(Hb + (size_t)b * 256 * 4096);

    // per-lane pre-swizzled stage source offsets (dest is linear)
    int ksrc[4], vsrc[4];
#pragma unroll
    for (int t = 0; t < 4; ++t) {
        int d = (w * 4 + t) * 1024 + lane * 16;
        int row = d >> 9, col = d & 511;
        ksrc[t] = row * 512 + (col ^ ((row & 7) << 4));
        int r128 = d >> 7, wn = d & 127;
        int wp = wn ^ ((r128 & 7) << 4);
        vsrc[t] = ((r128 * 2 + (wp >> 6)) << 13) + (wp & 63);
    }

#define STAGE(bufn, I0)                                                         \
    do {                                                                        \
        const char* kb_ = Fb + (size_t)(I0) * 512;                              \
        const char* vb_ = Hbb + (size_t)(I0) * 2;                               \
        char* kl = (char*)Kd[bufn];                                             \
        char* vl = (char*)Vd[bufn];                                             \
        _Pragma("unroll") for (int t = 0; t < 4; ++t)                           \
            gload16(kb_ + ksrc[t], kl + (w * 4 + t) * 1024);                    \
        _Pragma("unroll") for (int t = 0; t < 4; ++t)                           \
            gload16(vb_ + vsrc[t], vl + (w * 4 + t) * 1024);                    \
    } while (0)

    int i0beg = ks * 2048;
    STAGE(0, i0beg);   // prologue
    __syncthreads();   // drains vmcnt(0): tile 0 ready

    for (int it = 0; it < 64; ++it) {
        int cur = it & 1;
        if (it + 1 < 64) STAGE(cur ^ 1, i0beg + (it + 1) * 32);  // fly under compute

        const char* Kl = (const char*)Kd[cur];
        const char* Vb = (const char*)Vd[cur] + vlc;

        // ---- QK^T swapped: A = K (rows = keys), B = Q. (byte-identical to r14)
        // s0[q] = S[key 4g+q][query r], s1[q] = S[key 16+4g+q][query r]
        f32x4 s0 = {0.f, 0.f, 0.f, 0.f};
        f32x4 s1 = {0.f, 0.f, 0.f, 0.f};
        __builtin_amdgcn_s_setprio(1);
        {
            const char* kr = Kl + r * 512;
            int sw = (r & 7) << 4;
#pragma unroll
            for (int k = 0; k < 8; ++k) {
                f16x8 ka = *reinterpret_cast<const f16x8*>(kr + ((k * 64 + 16 * g) ^ sw));
                s0 = MFMA16(ka, Qf[k], s0);
            }
        }
        {
            const char* kr = Kl + (16 + r) * 512;
            int sw = (r & 7) << 4;  // (16+r)&7 == r&7
#pragma unroll
            for (int k = 0; k < 8; ++k) {
                f16x8 ka = *reinterpret_cast<const f16x8*>(kr + ((k * 64 + 16 * g) ^ sw));
                s1 = MFMA16(ka, Qf[k], s1);
            }
        }
        __builtin_amdgcn_s_setprio(0);

        // ---- softmax: lane holds 8 scores of query r; max reduced over g-lanes;
        //      l stays LANE-PARTIAL (reduced once after the loop) ----
        float v = fmaxf(fmaxf(fmaxf(s0[0], s0[1]), fmaxf(s0[2], s0[3])),
                        fmaxf(fmaxf(s1[0], s1[1]), fmaxf(s1[2], s1[3])));
        v = fmaxf(v, __shfl_xor(v, 16));
        v = fmaxf(v, __shfl_xor(v, 32));
        float grow = v - m;
        if (__all(grow <= 8.0f)) {  // T13 defer-max: skip rescale
#pragma unroll
            for (int q = 0; q < 4; ++q) {
                s0[q] = exp2f((s0[q] - m) * L2E);
                s1[q] = exp2f((s1[q] - m) * L2E);
            }
            l += (s0[0] + s0[1] + s0[2] + s0[3]) + (s1[0] + s1[1] + s1[2] + s1[3]);
        } else {
            float mn = fmaxf(m, v);
            float corr = exp2f((m - mn) * L2E);
            m = mn;
#pragma unroll
            for (int q = 0; q < 4; ++q) {
                s0[q] = exp2f((s0[q] - m) * L2E);
                s1[q] = exp2f((s1[q] - m) * L2E);
            }
            l = l * corr + (s0[0] + s0[1] + s0[2] + s0[3]) + (s1[0] + s1[1] + s1[2] + s1[3]);
#pragma unroll
            for (int ct = 0; ct < 16; ++ct) O[ct] *= corr;  // whole lane = one query
        }

        // ---- P -> PV B-frag: LANE-LOCAL (V keys permuted by conv_h) ----
        union { u32 wd[4]; f16x8 fr; } pu;
        pu.wd[0] = cvtpk(s0[0], s0[1]);
        pu.wd[1] = cvtpk(s0[2], s0[3]);
        pu.wd[2] = cvtpk(s1[0], s1[1]);
        pu.wd[3] = cvtpk(s1[2], s1[3]);

        // ---- PV: O[c][j] += V[c][slot] * P[slot][j]; A = V (imm offsets) ----
        __builtin_amdgcn_s_setprio(1);
#pragma unroll
        for (int ct = 0; ct < 16; ++ct) {
            f16x8 vb = *reinterpret_cast<const f16x8*>(Vb + ct * 1024);
            O[ct] = MFMA16(vb, pu.fr, O[ct]);
        }
        __builtin_amdgcn_s_setprio(0);

        __syncthreads();  // drains vmcnt (next tile landed during compute); buffer reuse safe
    }
#undef STAGE

    // ---- finalize: reduce lane-partial l across the 4 g-lanes, normalize, store ----
    l += __shfl_xor(l, 16);
    l += __shfl_xor(l, 32);
    float inv = 1.f / l;
    size_t mrow = (size_t)ks * 16384 + b * 4096 + j0 + r;
#pragma unroll
    for (int ct = 0; ct < 16; ++ct) {
        short4v pk;
#pragma unroll
        for (int q = 0; q < 4; ++q) pk[q] = (short)h16(O[ct][q] * inv);
        *reinterpret_cast<short4v*>(OP + mrow * 256 + ct * 16 + 4 * g) = pk;
    }
    if (g == 0) {
        size_t mi = mrow * 2;
        ML[mi] = m;
        ML[mi + 1] = l;
    }
}

// ---------------- merge key-splits (x2, normalized partials) -> OT fp16 [m][c] ----------------
__global__ __launch_bounds__(256) void k_merge(
    const u16* __restrict__ OP, const float* __restrict__ ML, u16* __restrict__ OT) {
    int t = blockIdx.x * 256 + threadIdx.x;  // 524288 threads
    int m = t >> 5;
    int c0 = (t & 31) * 8;
    const float L2E = 1.4426950408889634f;
    float m0 = ML[(size_t)m * 2], l0 = ML[(size_t)m * 2 + 1];
    float m1 = ML[((size_t)16384 + m) * 2], l1 = ML[((size_t)16384 + m) * 2 + 1];
    float M = fmaxf(m0, m1);
    float wl0 = exp2f((m0 - M) * L2E) * l0;
    float wl1 = exp2f((m1 - M) * L2E) * l1;
    float inv = 1.f / (wl0 + wl1);
    f16x8 v0 = ldh8(OP + (size_t)m * 256 + c0);
    f16x8 v1 = ldh8(OP + ((size_t)16384 + m) * 256 + c0);
    short8 outp;
#pragma unroll
    for (int j = 0; j < 8; ++j)
        outp[j] = (short)h16((wl0 * (float)v0[j] + wl1 * (float)v1[j]) * inv);
    *reinterpret_cast<short8*>(OT + (size_t)m * 256 + c0) = outp;
}

// ---------------- final conv: fp16 MFMA, f32 out ----------------
__global__ __launch_bounds__(256) void k_conv_out(
    const u16* __restrict__ WV, const u16* __restrict__ OT,
    const float* __restrict__ bv, float* __restrict__ out) {
    int bidn = blockIdx.x & 255, bido = blockIdx.x >> 8;
    int w = threadIdx.x >> 6, lane = threadIdx.x & 63, r = lane & 15, g = lane >> 4;
    int o0 = bido * 64 + w * 16, n0 = bidn * 64;
    f32x4 acc[4];
#pragma unroll
    for (int i = 0; i < 4; ++i) acc[i] = {0.f, 0.f, 0.f, 0.f};
    const u16* arow = WV + (size_t)(o0 + r) * 256;
#pragma unroll
    for (int ks = 0; ks < 8; ++ks) {
        int k0 = ks * 32 + 8 * g;
        f16x8 a = ldh8(arow + k0);
#pragma unroll
        for (int ntl = 0; ntl < 4; ++ntl) {
            f16x8 bb = ldh8(OT + (size_t)(n0 + ntl * 16 + r) * 256 + k0);
            acc[ntl] = MFMA16(a, bb, acc[ntl]);
        }
    }
#pragma unroll
    for (int ntl = 0; ntl < 4; ++ntl) {
#pragma unroll
        for (int q = 0; q < 4; ++q) {
            int o = o0 + 4 * g + q;
            int nf = n0 + ntl * 16 + r;
            int bb = nf >> 12, n = nf & 4095;
            out[((size_t)(bb * 256 + o)) * 4096 + n] = acc[ntl][q] + bv[o];
        }
    }
}

extern "C" void kernel_launch(void* const* d_in, const int* in_sizes, int n_in,
                              void* d_out, int out_size, void* d_ws, size_t ws_size,
                              hipStream_t stream) {
    const float* x  = (const float*)d_in[0];
    const float* Wf = (const float*)d_in[1];
    const float* bf = (const float*)d_in[2];
    const float* Wg = (const float*)d_in[3];
    const float* bg = (const float*)d_in[4];
    const float* Wh = (const float*)d_in[5];
    const float* bh = (const float*)d_in[6];
    const float* Wv = (const float*)d_in[7];
    const float* bv = (const float*)d_in[8];
    float* out = (float*)d_out;
    char* ws = (char*)d_ws;

    u16* WF = (u16*)(ws + OFF_WF);
    u16* WG = (u16*)(ws + OFF_WG);
    u16* WH = (u16*)(ws + OFF_WH);
    u16* WV = (u16*)(ws + OFF_WV);
    float* ML = (float*)(ws + OFF_ML);
    u16* F  = (u16*)(ws + OFF_F);
    u16* G  = (u16*)(ws + OFF_G);
    u16* H  = (u16*)(ws + OFF_H);
    u16* XT = (u16*)(ws + OFF_XT);
    u16* OP = (u16*)(ws + OFF_OP);   // aliases XT (dead after convs)
    u16* OT = (u16*)(ws + OFF_OT);   // aliases F (dead after attn)

    k_prep_w<<<256, 256, 0, stream>>>(Wf, Wg, Wh, Wv, WF, WG, WH, WV);
    k_prep_x<<<1024, 256, 0, stream>>>(x, XT);
    k_conv_fg<<<1024, 256, 0, stream>>>(XT, WF, WG, bf, bg, F, G);
    k_conv_h<<<1024, 256, 0, stream>>>(WH, XT, bh, H);
    k_attn<<<512, 256, 0, stream>>>(F, G, H, OP, ML);
    k_merge<<<2048, 256, 0, stream>>>(OP, ML, OT);
    k_conv_out<<<1024, 256, 0, stream>>>(WV, OT, bv, out);
}